// Round 17
// baseline (1150.332 us; speedup 1.0000x reference)
//
#include <hip/hip_runtime.h>

#define B_ 1024
#define T_ 366
#define NS_ 365
#define CD_ 24
#define NTASK (B_ * NS_)

__device__ __forceinline__ float sigm2(float x) {   // x pre-scaled by log2(e)
    return __fdividef(1.f, 1.f + exp2f(-x));
}

// ---- pack (weights pre-scaled by log2e so gates use native exp2):
//      Wpk[e][32] = {w0..23, rad, bias}; Apk[r][32] = {w0..28, bias} ----
__global__ void mclstm_pack(const float* __restrict__ Wr, const float* __restrict__ br,
                            const float* __restrict__ Wp, const float* __restrict__ bp,
                            const float* __restrict__ Wc, const float* __restrict__ bc,
                            const float* __restrict__ Wa, const float* __restrict__ ba,
                            float* __restrict__ Wpk, float* __restrict__ Apk) {
    const float S = 1.44269504088896341f;   // log2(e)
    const int e = blockIdx.x * 64 + threadIdx.x;
    if (e < 576) {
#pragma unroll
        for (int k = 0; k < 24; ++k) Wpk[e * 32 + k] = Wr[e * 29 + k] * S;
        Wpk[e * 32 + 24] = Wr[e * 29 + 25] * S;
        Wpk[e * 32 + 25] = br[e] * S;
#pragma unroll
        for (int k = 26; k < 32; ++k) Wpk[e * 32 + k] = 0.f;
    } else if (e < 625) {
        const int r = e - 576;
#pragma unroll
        for (int k = 0; k < 29; ++k)
            Apk[r * 32 + k] = ((r < 24) ? Wp[r * 29 + k] : (r < 48) ? Wc[(r - 24) * 29 + k] : Wa[k]) * S;
        Apk[r * 32 + 29] = ((r < 24) ? bp[r] : (r < 48) ? bc[r - 24] : ba[0]) * S;
        Apk[r * 32 + 30] = 0.f; Apk[r * 32 + 31] = 0.f;
    }
}

// ---- main: 1 chain / 192-thr block (3 waves, 3 rows/lane, no ext rows);
//      wave2 = aux; fused softmax+colsum on waves 0/1; reg-prefetched X/ORY ----
__global__ __attribute__((amdgpu_flat_work_group_size(192, 192), amdgpu_waves_per_eu(3, 3)))
void mclstm_main(const float* __restrict__ X, const float* __restrict__ ORY,
                 const float* __restrict__ Wpk, const float* __restrict__ Apk,
                 float* __restrict__ Ccell, float* __restrict__ Cconv)
{
    __shared__ __align__(16) float zb1[672], zb2[672];   // z row-major, stride 28
    __shared__ __align__(16) float pb1[672], pb2[672];   // scaled P col-major, stride 28
    __shared__ __align__(16) float cbuf[24];
    __shared__ float cmb[24];

    const int tid = threadIdx.x;
    const int l = tid & 63, wv = tid >> 6;
    const int b = blockIdx.x;

    // 3 register-resident redis rows: e = tid + 192*j (covers 0..575 exactly)
    float wrg[3][24], wrad[3], brg[3];
    int za[3];
#pragma unroll
    for (int j = 0; j < 3; ++j) {
        const int e = tid + 192 * j;
        const float4* wp = (const float4*)(Wpk + (size_t)e * 32);
#pragma unroll
        for (int q = 0; q < 6; ++q) {
            const float4 v = wp[q];
            wrg[j][4*q] = v.x; wrg[j][4*q+1] = v.y; wrg[j][4*q+2] = v.z; wrg[j][4*q+3] = v.w;
        }
        const float4 t = wp[6];
        wrad[j] = t.x; brg[j] = t.y;
        za[j] = (e / 24) * 28 + (e % 24);
    }
    // aux row: wave2 only
    float ext[32];
    if (wv == 2) {
        const float4* p = (const float4*)(Apk + (size_t)((l < 49) ? l : 48) * 32);
#pragma unroll
        for (int q = 0; q < 8; ++q) {
            const float4 v = p[q];
            ext[4*q] = v.x; ext[4*q+1] = v.y; ext[4*q+2] = v.z; ext[4*q+3] = v.w;
        }
    }

    const int rc = l >> 1, hh = l & 1;

    const float* xrow = X + (size_t)b * T_ * 4;
    const float* orow = ORY + (size_t)b * T_ * 7;

    if (tid < 24) cbuf[tid] = 0.f;
    __syncthreads();

    float Ncum = 0.f, rp = 0.f;
    float4 xc = *(const float4*)xrow;   // step-u X in registers
    float dvsc = orow[0];

    for (int u = 0; u <= NS_; ++u) {
        const bool do1 = (u < NS_), doCv = (u > 0);

        // prefetch step u+1 (hidden under the whole step)
        const int un = (u + 1 <= NS_) ? (u + 1) : NS_;
        const float4 xn = *(const float4*)(xrow + un * 4);
        const float dn = orow[un * 7];

        const float ra = xc.x;

        // C_u broadcast + kind1 multiplier captured pre-barrier
        float Cs[24];
#pragma unroll
        for (int q = 0; q < 6; ++q) {
            const float4 v = ((const float4*)cbuf)[q];
            Cs[4*q] = v.x; Cs[4*q+1] = v.y; Cs[4*q+2] = v.z; Cs[4*q+3] = v.w;
        }
        const float mlt1 = cbuf[rc];

        // ---- Phase A: shared dots (3 rows); z1 = D + wrad*ra, z2 = D + wrad*rp ----
#pragma unroll
        for (int j = 0; j < 3; ++j) {
            float p0 = brg[j], p1 = 0.f, p2 = 0.f, p3 = 0.f;
#pragma unroll
            for (int k = 0; k < 24; k += 4) {
                p0 = fmaf(wrg[j][k],   Cs[k],   p0);
                p1 = fmaf(wrg[j][k+1], Cs[k+1], p1);
                p2 = fmaf(wrg[j][k+2], Cs[k+2], p2);
                p3 = fmaf(wrg[j][k+3], Cs[k+3], p3);
            }
            const float D = (p0 + p1) + (p2 + p3);
            if (do1)  zb1[za[j]] = fmaf(wrad[j], ra, D);
            if (doCv) zb2[za[j]] = fmaf(wrad[j], rp, D);
        }

        if (wv == 2 && do1) {
            // aux row + in-wave part/cons/assim -> cmid (lanes 0..23); z pre-scaled
            Ncum += xc.w;
            const float tave = 0.5f * (xc.y + xc.z);
            const float clm = fminf(fmaxf(tave * 50.f, 10.f), 40.f);
            const float eff = 0.54f - (clm - 10.f) * (0.18f / 30.f);
            const float cpot = ra * (eff * (2.f * 0.5f / 3.6f * (12.f / 44.f)));

            float z = ext[29];
#pragma unroll
            for (int k = 0; k < 24; ++k) z = fmaf(ext[k], Cs[k], z);
            z = fmaf(ext[24], dvsc, z);
            z = fmaf(ext[25], ra, z);
            z = fmaf(ext[26], xc.y, z);
            z = fmaf(ext[27], xc.z, z);
            z = fmaf(ext[28], Ncum, z);

            float pm = (l < 24) ? z : -1e30f;
#pragma unroll
            for (int o = 1; o < 32; o <<= 1) pm = fmaxf(pm, __shfl_xor(pm, o, 32));
            float pe = (l < 24) ? exp2f(z - pm) : 0.f;
            float ps = pe;
#pragma unroll
            for (int o = 1; o < 32; o <<= 1) ps += __shfl_xor(ps, o, 32);
            const float conz = __shfl(z, 24 + (l & 31), 64);
            const float asmz = __shfl(z, 48, 64);
            if (l < 24) {
                const float part = __fdividef(pe, ps);
                cmb[l] = (cbuf[l] + sigm2(asmz) * cpot * part) * (1.f - sigm2(conz));
            }
        }
        __syncthreads();   // B1: zb + cmb ready

        // ---- FUSED softmax + colsum: wave0=kind0, wave1=kind1 (same-wave LDS ordered) ----
        {
            const bool act = (wv < 2) && (l < 48) && (wv ? doCv : do1);
            if (act) {
                const float* zs = wv ? zb2 : zb1;
                float* pbk = wv ? pb2 : pb1;
                const float4* z4 = (const float4*)(zs + rc * 28 + hh * 12);
                float z[12];
#pragma unroll
                for (int q = 0; q < 3; ++q) {
                    const float4 v = z4[q];
                    z[4*q] = v.x; z[4*q+1] = v.y; z[4*q+2] = v.z; z[4*q+3] = v.w;
                }
                float m = z[0];
#pragma unroll
                for (int i = 1; i < 12; ++i) m = fmaxf(m, z[i]);
                m = fmaxf(m, __shfl_xor(m, 1));
                float ss = 0.f;
#pragma unroll
                for (int i = 0; i < 12; ++i) { z[i] = exp2f(z[i] - m); ss += z[i]; }
                ss += __shfl_xor(ss, 1);
                const float mult = wv ? mlt1 : cmb[rc];
                const float f = __fdividef(mult, ss);
#pragma unroll
                for (int i = 0; i < 12; ++i) pbk[(hh * 12 + i) * 28 + rc] = z[i] * f;

                // colsum (same-wave RAW; HW orders LDS ops within a wave)
                float ssum = 0.f;
                const float4* p4 = (const float4*)(pbk + rc * 28 + hh * 12);
#pragma unroll
                for (int i = 0; i < 3; ++i) {
                    const float4 v = p4[i];
                    ssum += (v.x + v.y) + (v.z + v.w);
                }
                ssum += __shfl_xor(ssum, 1);
                if (hh == 0) {
                    if (wv) {
                        Cconv[((size_t)b * NS_ + (u - 1)) * CD_ + rc] = ssum;
                    } else {
                        cbuf[rc] = ssum;
                        Ccell[((size_t)b * NS_ + u) * CD_ + rc] = ssum;
                    }
                }
            }
        }
        __syncthreads();   // B2: C(t+1) visible; zb free for next step
        rp = ra; xc = xn; dvsc = dn;
    }
}

// ---- epilogue: all_day from Ccell (streaming, trivially parallel) ----
__global__ __launch_bounds__(256) void mclstm_allday(
    const float* __restrict__ ORY, const float* __restrict__ c2a,
    const float* __restrict__ g2y, const float* __restrict__ Ccell,
    float* __restrict__ allday) {
    const int tid = blockIdx.x * 256 + threadIdx.x;
    if (tid < B_) {
#pragma unroll
        for (int k = 0; k < 7; ++k)
            allday[(size_t)tid * T_ * 7 + k] = ORY[(size_t)tid * T_ * 7 + k];
    }
    if (tid >= NTASK) return;
    const int b = tid / NS_;
    const int t = tid - b * NS_;

    const float* Cp = Ccell + (size_t)tid * CD_;
    float C[24];
#pragma unroll
    for (int q = 0; q < 6; ++q) {
        const float4 v = *(const float4*)(Cp + 4 * q);
        C[4 * q] = v.x; C[4 * q + 1] = v.y; C[4 * q + 2] = v.z; C[4 * q + 3] = v.w;
    }
    float pai = 0.f;
#pragma unroll
    for (int c = 0; c < 24; ++c) pai += fabsf(C[c] * c2a[c]);
    float lea = 0.f, ste = 0.f, gra = 0.f, yie = 0.f;
#pragma unroll
    for (int c = 0; c < 8; ++c) lea += C[c];
#pragma unroll
    for (int c = 8; c < 16; ++c) ste += C[c];
#pragma unroll
    for (int c = 16; c < 24; ++c) { gra += C[c]; yie += fabsf(C[c] * g2y[c - 16]); }
    lea /= 0.419f; ste /= 0.431f; gra /= 0.487f; yie /= 0.487f;
    const float agb = lea + ste + gra;

    float* ad = allday + ((size_t)b * T_ + (t + 1)) * 7;
    ad[0] = ORY[((size_t)b * T_ + (t + 1)) * 7];
    ad[1] = pai; ad[2] = lea; ad[3] = ste; ad[4] = gra; ad[5] = agb; ad[6] = yie;
}

extern "C" void kernel_launch(void* const* d_in, const int* in_sizes, int n_in,
                              void* d_out, int out_size, void* d_ws, size_t ws_size,
                              hipStream_t stream) {
    const float* X   = (const float*)d_in[0];
    const float* ORY = (const float*)d_in[1];
    const float* Wr  = (const float*)d_in[2];
    const float* br  = (const float*)d_in[3];
    const float* Wp  = (const float*)d_in[4];
    const float* bp  = (const float*)d_in[5];
    const float* Wc  = (const float*)d_in[6];
    const float* bc  = (const float*)d_in[7];
    const float* Wa  = (const float*)d_in[8];
    const float* ba  = (const float*)d_in[9];
    const float* c2a = (const float*)d_in[10];
    const float* g2y = (const float*)d_in[11];

    float* allday = (float*)d_out;
    float* Ccell  = allday + (size_t)B_ * T_ * 7;
    float* Cconv  = Ccell + (size_t)B_ * NS_ * CD_;

    float* Wpk = (float*)d_ws;            // 576*32 floats
    float* Apk = Wpk + 576 * 32;          // 49*32 floats

    hipLaunchKernelGGL(mclstm_pack, dim3(10), dim3(64), 0, stream,
                       Wr, br, Wp, bp, Wc, bc, Wa, ba, Wpk, Apk);
    hipLaunchKernelGGL(mclstm_main, dim3(B_), dim3(192), 0, stream,
                       X, ORY, Wpk, Apk, Ccell, Cconv);
    hipLaunchKernelGGL(mclstm_allday, dim3(NTASK / 256), dim3(256), 0, stream,
                       ORY, c2a, g2y, Ccell, allday);
}

// Round 18
// 847.309 us; speedup vs baseline: 1.3576x; 1.3576x over previous
//
#include <hip/hip_runtime.h>

#define B_ 1024
#define T_ 366
#define NS_ 365
#define CD_ 24
#define NTASK (B_ * NS_)

__device__ __forceinline__ float sigm2(float x) {   // x pre-scaled by log2(e)
    return __fdividef(1.f, 1.f + exp2f(-x));
}

// ---- pack (weights pre-scaled by log2e so gates use native exp2):
//      Wpk[e][32] = {w0..23, rad, bias}; Apk[r][32] = {w0..28, bias} ----
__global__ void mclstm_pack(const float* __restrict__ Wr, const float* __restrict__ br,
                            const float* __restrict__ Wp, const float* __restrict__ bp,
                            const float* __restrict__ Wc, const float* __restrict__ bc,
                            const float* __restrict__ Wa, const float* __restrict__ ba,
                            float* __restrict__ Wpk, float* __restrict__ Apk) {
    const float S = 1.44269504088896341f;   // log2(e)
    const int e = blockIdx.x * 64 + threadIdx.x;
    if (e < 576) {
#pragma unroll
        for (int k = 0; k < 24; ++k) Wpk[e * 32 + k] = Wr[e * 29 + k] * S;
        Wpk[e * 32 + 24] = Wr[e * 29 + 25] * S;
        Wpk[e * 32 + 25] = br[e] * S;
#pragma unroll
        for (int k = 26; k < 32; ++k) Wpk[e * 32 + k] = 0.f;
    } else if (e < 625) {
        const int r = e - 576;
#pragma unroll
        for (int k = 0; k < 29; ++k)
            Apk[r * 32 + k] = ((r < 24) ? Wp[r * 29 + k] : (r < 48) ? Wc[(r - 24) * 29 + k] : Wa[k]) * S;
        Apk[r * 32 + 29] = ((r < 24) ? bp[r] : (r < 48) ? bc[r - 24] : ba[0]) * S;
        Apk[r * 32 + 30] = 0.f; Apk[r * 32 + 31] = 0.f;
    }
}

// ---- main: 1 chain / 256-thr block (4 waves, 2 rows/lane);
//      wave2 = ext redis rows (phase A), wave3 = aux (phase A),
//      waves 0/1 = fused softmax+colsum (after B1); reg-prefetched X/ORY ----
__global__ __attribute__((amdgpu_flat_work_group_size(256, 256), amdgpu_waves_per_eu(4, 4)))
void mclstm_main(const float* __restrict__ X, const float* __restrict__ ORY,
                 const float* __restrict__ Wpk, const float* __restrict__ Apk,
                 float* __restrict__ Ccell, float* __restrict__ Cconv)
{
    __shared__ __align__(16) float zb1[672], zb2[672];   // z row-major, stride 28
    __shared__ __align__(16) float pb1[672], pb2[672];   // scaled P col-major, stride 28
    __shared__ __align__(16) float cbuf[24];
    __shared__ float cmb[24];

    const int tid = threadIdx.x;
    const int l = tid & 63, wv = tid >> 6;
    const int b = blockIdx.x;

    // 2 register-resident redis rows: e = tid + 256*j (covers 0..511)
    float wrg[2][24], wrad[2], brg[2];
    int za[2];
#pragma unroll
    for (int j = 0; j < 2; ++j) {
        const int e = tid + 256 * j;
        const float4* wp = (const float4*)(Wpk + (size_t)e * 32);
#pragma unroll
        for (int q = 0; q < 6; ++q) {
            const float4 v = wp[q];
            wrg[j][4*q] = v.x; wrg[j][4*q+1] = v.y; wrg[j][4*q+2] = v.z; wrg[j][4*q+3] = v.w;
        }
        const float4 t = wp[6];
        wrad[j] = t.x; brg[j] = t.y;
        za[j] = (e / 24) * 28 + (e % 24);
    }
    // extra row: wave2 = redis row 512+l; wave3 = aux row min(l,48)
    float ext[32];
    if (wv >= 2) {
        const float4* p = (const float4*)((wv == 2) ? (Wpk + (size_t)(512 + l) * 32)
                                                    : (Apk + (size_t)((l < 49) ? l : 48) * 32));
#pragma unroll
        for (int q = 0; q < 8; ++q) {
            const float4 v = p[q];
            ext[4*q] = v.x; ext[4*q+1] = v.y; ext[4*q+2] = v.z; ext[4*q+3] = v.w;
        }
    }
    const int za4 = ((512 + l) / 24) * 28 + (512 + l) % 24;

    const int rc = l >> 1, hh = l & 1;

    const float* xrow = X + (size_t)b * T_ * 4;
    const float* orow = ORY + (size_t)b * T_ * 7;

    if (tid < 24) cbuf[tid] = 0.f;
    __syncthreads();

    float Ncum = 0.f, rp = 0.f;
    float4 xc = *(const float4*)xrow;   // step-u X in registers
    float dvsc = orow[0];

    for (int u = 0; u <= NS_; ++u) {
        const bool do1 = (u < NS_), doCv = (u > 0);

        // prefetch step u+1 (hidden under the whole step)
        const int un = (u + 1 <= NS_) ? (u + 1) : NS_;
        const float4 xn = *(const float4*)(xrow + un * 4);
        const float dn = orow[un * 7];

        const float ra = xc.x;

        // C_u broadcast + kind1 multiplier captured pre-barrier
        float Cs[24];
#pragma unroll
        for (int q = 0; q < 6; ++q) {
            const float4 v = ((const float4*)cbuf)[q];
            Cs[4*q] = v.x; Cs[4*q+1] = v.y; Cs[4*q+2] = v.z; Cs[4*q+3] = v.w;
        }
        const float mlt1 = cbuf[rc];

        // ---- Phase A: shared dots (2 rows); z1 = D + wrad*ra, z2 = D + wrad*rp ----
#pragma unroll
        for (int j = 0; j < 2; ++j) {
            float p0 = brg[j], p1 = 0.f, p2 = 0.f, p3 = 0.f;
#pragma unroll
            for (int k = 0; k < 24; k += 4) {
                p0 = fmaf(wrg[j][k],   Cs[k],   p0);
                p1 = fmaf(wrg[j][k+1], Cs[k+1], p1);
                p2 = fmaf(wrg[j][k+2], Cs[k+2], p2);
                p3 = fmaf(wrg[j][k+3], Cs[k+3], p3);
            }
            const float D = (p0 + p1) + (p2 + p3);
            if (do1)  zb1[za[j]] = fmaf(wrad[j], ra, D);
            if (doCv) zb2[za[j]] = fmaf(wrad[j], rp, D);
        }

        if (wv == 2) {
            // ext redis row (rows 512..575)
            float p0 = ext[25], p1 = 0.f, p2 = 0.f, p3 = 0.f;
#pragma unroll
            for (int k = 0; k < 24; k += 4) {
                p0 = fmaf(ext[k],   Cs[k],   p0);
                p1 = fmaf(ext[k+1], Cs[k+1], p1);
                p2 = fmaf(ext[k+2], Cs[k+2], p2);
                p3 = fmaf(ext[k+3], Cs[k+3], p3);
            }
            const float D = (p0 + p1) + (p2 + p3);
            if (do1)  zb1[za4] = fmaf(ext[24], ra, D);
            if (doCv) zb2[za4] = fmaf(ext[24], rp, D);
        } else if (wv == 3 && do1) {
            // aux row + in-wave part/cons/assim -> cmid (lanes 0..23); z pre-scaled
            Ncum += xc.w;
            const float tave = 0.5f * (xc.y + xc.z);
            const float clm = fminf(fmaxf(tave * 50.f, 10.f), 40.f);
            const float eff = 0.54f - (clm - 10.f) * (0.18f / 30.f);
            const float cpot = ra * (eff * (2.f * 0.5f / 3.6f * (12.f / 44.f)));

            float z = ext[29];
#pragma unroll
            for (int k = 0; k < 24; ++k) z = fmaf(ext[k], Cs[k], z);
            z = fmaf(ext[24], dvsc, z);
            z = fmaf(ext[25], ra, z);
            z = fmaf(ext[26], xc.y, z);
            z = fmaf(ext[27], xc.z, z);
            z = fmaf(ext[28], Ncum, z);

            float pm = (l < 24) ? z : -1e30f;
#pragma unroll
            for (int o = 1; o < 32; o <<= 1) pm = fmaxf(pm, __shfl_xor(pm, o, 32));
            float pe = (l < 24) ? exp2f(z - pm) : 0.f;
            float ps = pe;
#pragma unroll
            for (int o = 1; o < 32; o <<= 1) ps += __shfl_xor(ps, o, 32);
            const float conz = __shfl(z, 24 + (l & 31), 64);
            const float asmz = __shfl(z, 48, 64);
            if (l < 24) {
                const float part = __fdividef(pe, ps);
                cmb[l] = (cbuf[l] + sigm2(asmz) * cpot * part) * (1.f - sigm2(conz));
            }
        }
        __syncthreads();   // B1: zb + cmb ready

        // ---- FUSED softmax + colsum: wave0=kind0, wave1=kind1 (same-wave LDS ordered) ----
        {
            const bool act = (wv < 2) && (l < 48) && (wv ? doCv : do1);
            if (act) {
                const float* zs = wv ? zb2 : zb1;
                float* pbk = wv ? pb2 : pb1;
                const float4* z4 = (const float4*)(zs + rc * 28 + hh * 12);
                float z[12];
#pragma unroll
                for (int q = 0; q < 3; ++q) {
                    const float4 v = z4[q];
                    z[4*q] = v.x; z[4*q+1] = v.y; z[4*q+2] = v.z; z[4*q+3] = v.w;
                }
                float m = z[0];
#pragma unroll
                for (int i = 1; i < 12; ++i) m = fmaxf(m, z[i]);
                m = fmaxf(m, __shfl_xor(m, 1));
                float ss = 0.f;
#pragma unroll
                for (int i = 0; i < 12; ++i) { z[i] = exp2f(z[i] - m); ss += z[i]; }
                ss += __shfl_xor(ss, 1);
                const float mult = wv ? mlt1 : cmb[rc];
                const float f = __fdividef(mult, ss);
#pragma unroll
                for (int i = 0; i < 12; ++i) pbk[(hh * 12 + i) * 28 + rc] = z[i] * f;

                // colsum (same-wave RAW; HW orders LDS ops within a wave)
                float ssum = 0.f;
                const float4* p4 = (const float4*)(pbk + rc * 28 + hh * 12);
#pragma unroll
                for (int i = 0; i < 3; ++i) {
                    const float4 v = p4[i];
                    ssum += (v.x + v.y) + (v.z + v.w);
                }
                ssum += __shfl_xor(ssum, 1);
                if (hh == 0) {
                    if (wv) {
                        Cconv[((size_t)b * NS_ + (u - 1)) * CD_ + rc] = ssum;
                    } else {
                        cbuf[rc] = ssum;
                        Ccell[((size_t)b * NS_ + u) * CD_ + rc] = ssum;
                    }
                }
            }
        }
        __syncthreads();   // B2: C(t+1) visible; zb free for next step
        rp = ra; xc = xn; dvsc = dn;
    }
}

// ---- epilogue: all_day from Ccell (streaming, trivially parallel) ----
__global__ __launch_bounds__(256) void mclstm_allday(
    const float* __restrict__ ORY, const float* __restrict__ c2a,
    const float* __restrict__ g2y, const float* __restrict__ Ccell,
    float* __restrict__ allday) {
    const int tid = blockIdx.x * 256 + threadIdx.x;
    if (tid < B_) {
#pragma unroll
        for (int k = 0; k < 7; ++k)
            allday[(size_t)tid * T_ * 7 + k] = ORY[(size_t)tid * T_ * 7 + k];
    }
    if (tid >= NTASK) return;
    const int b = tid / NS_;
    const int t = tid - b * NS_;

    const float* Cp = Ccell + (size_t)tid * CD_;
    float C[24];
#pragma unroll
    for (int q = 0; q < 6; ++q) {
        const float4 v = *(const float4*)(Cp + 4 * q);
        C[4 * q] = v.x; C[4 * q + 1] = v.y; C[4 * q + 2] = v.z; C[4 * q + 3] = v.w;
    }
    float pai = 0.f;
#pragma unroll
    for (int c = 0; c < 24; ++c) pai += fabsf(C[c] * c2a[c]);
    float lea = 0.f, ste = 0.f, gra = 0.f, yie = 0.f;
#pragma unroll
    for (int c = 0; c < 8; ++c) lea += C[c];
#pragma unroll
    for (int c = 8; c < 16; ++c) ste += C[c];
#pragma unroll
    for (int c = 16; c < 24; ++c) { gra += C[c]; yie += fabsf(C[c] * g2y[c - 16]); }
    lea /= 0.419f; ste /= 0.431f; gra /= 0.487f; yie /= 0.487f;
    const float agb = lea + ste + gra;

    float* ad = allday + ((size_t)b * T_ + (t + 1)) * 7;
    ad[0] = ORY[((size_t)b * T_ + (t + 1)) * 7];
    ad[1] = pai; ad[2] = lea; ad[3] = ste; ad[4] = gra; ad[5] = agb; ad[6] = yie;
}

extern "C" void kernel_launch(void* const* d_in, const int* in_sizes, int n_in,
                              void* d_out, int out_size, void* d_ws, size_t ws_size,
                              hipStream_t stream) {
    const float* X   = (const float*)d_in[0];
    const float* ORY = (const float*)d_in[1];
    const float* Wr  = (const float*)d_in[2];
    const float* br  = (const float*)d_in[3];
    const float* Wp  = (const float*)d_in[4];
    const float* bp  = (const float*)d_in[5];
    const float* Wc  = (const float*)d_in[6];
    const float* bc  = (const float*)d_in[7];
    const float* Wa  = (const float*)d_in[8];
    const float* ba  = (const float*)d_in[9];
    const float* c2a = (const float*)d_in[10];
    const float* g2y = (const float*)d_in[11];

    float* allday = (float*)d_out;
    float* Ccell  = allday + (size_t)B_ * T_ * 7;
    float* Cconv  = Ccell + (size_t)B_ * NS_ * CD_;

    float* Wpk = (float*)d_ws;            // 576*32 floats
    float* Apk = Wpk + 576 * 32;          // 49*32 floats

    hipLaunchKernelGGL(mclstm_pack, dim3(10), dim3(64), 0, stream,
                       Wr, br, Wp, bp, Wc, bc, Wa, ba, Wpk, Apk);
    hipLaunchKernelGGL(mclstm_main, dim3(B_), dim3(256), 0, stream,
                       X, ORY, Wpk, Apk, Ccell, Cconv);
    hipLaunchKernelGGL(mclstm_allday, dim3(NTASK / 256), dim3(256), 0, stream,
                       ORY, c2a, g2y, Ccell, allday);
}